// Round 1
// baseline (742.848 us; speedup 1.0000x reference)
//
#include <hip/hip_runtime.h>

#define N_NODES 50000
#define N_EDGES 800000
#define HID 128

// ---------------- zero agg + deg in workspace ----------------
__global__ __launch_bounds__(256) void zero_ws_k(float4* __restrict__ agg4,
                                                 float* __restrict__ deg) {
  const size_t stride = (size_t)gridDim.x * blockDim.x;
  const size_t i = (size_t)blockIdx.x * blockDim.x + threadIdx.x;
  const size_t n4 = (size_t)N_NODES * HID / 4;
  for (size_t v = i; v < n4; v += stride) agg4[v] = make_float4(0.f, 0.f, 0.f, 0.f);
  for (size_t v = i; v < N_NODES; v += stride) deg[v] = 0.f;
}

// ---------------- h = X @ W^T + b  (fp32 vector GEMM) ----------------
// 64x64 tile per block, 256 threads (16x16), 4x4 microtile, K chunked by 32.
// LDS stored transposed: As[k][row], Bs[k][col]; pad 68 keeps float4-aligned
// reads and spreads write banks.
__global__ __launch_bounds__(256) void gemm_k(const float* __restrict__ X,
                                              const float* __restrict__ W,
                                              const float* __restrict__ B,
                                              float* __restrict__ H) {
  __shared__ __align__(16) float As[32][68];
  __shared__ __align__(16) float Bs[32][68];
  const int t = threadIdx.x;
  const int tx = t & 15;
  const int ty = t >> 4;
  const int i0 = blockIdx.x * 64;
  const int j0 = blockIdx.y * 64;
  float acc[4][4] = {{0.f, 0.f, 0.f, 0.f}, {0.f, 0.f, 0.f, 0.f},
                     {0.f, 0.f, 0.f, 0.f}, {0.f, 0.f, 0.f, 0.f}};

  for (int kc = 0; kc < HID; kc += 32) {
#pragma unroll
    for (int it = 0; it < 2; ++it) {
      const int v = t + it * 256;  // 0..511
      const int row = v >> 3;      // 0..63
      const int c4 = v & 7;        // 8 float4 per row of 32 k-values
      float4 a = make_float4(0.f, 0.f, 0.f, 0.f);
      if (i0 + row < N_NODES)
        a = *(const float4*)(X + (size_t)(i0 + row) * HID + kc + c4 * 4);
      As[c4 * 4 + 0][row] = a.x;
      As[c4 * 4 + 1][row] = a.y;
      As[c4 * 4 + 2][row] = a.z;
      As[c4 * 4 + 3][row] = a.w;
      const float4 w = *(const float4*)(W + (size_t)(j0 + row) * HID + kc + c4 * 4);
      Bs[c4 * 4 + 0][row] = w.x;
      Bs[c4 * 4 + 1][row] = w.y;
      Bs[c4 * 4 + 2][row] = w.z;
      Bs[c4 * 4 + 3][row] = w.w;
    }
    __syncthreads();
#pragma unroll
    for (int k = 0; k < 32; ++k) {
      const float4 av = *(const float4*)&As[k][ty * 4];
      const float4 bv = *(const float4*)&Bs[k][tx * 4];
      acc[0][0] = fmaf(av.x, bv.x, acc[0][0]);
      acc[0][1] = fmaf(av.x, bv.y, acc[0][1]);
      acc[0][2] = fmaf(av.x, bv.z, acc[0][2]);
      acc[0][3] = fmaf(av.x, bv.w, acc[0][3]);
      acc[1][0] = fmaf(av.y, bv.x, acc[1][0]);
      acc[1][1] = fmaf(av.y, bv.y, acc[1][1]);
      acc[1][2] = fmaf(av.y, bv.z, acc[1][2]);
      acc[1][3] = fmaf(av.y, bv.w, acc[1][3]);
      acc[2][0] = fmaf(av.z, bv.x, acc[2][0]);
      acc[2][1] = fmaf(av.z, bv.y, acc[2][1]);
      acc[2][2] = fmaf(av.z, bv.z, acc[2][2]);
      acc[2][3] = fmaf(av.z, bv.w, acc[2][3]);
      acc[3][0] = fmaf(av.w, bv.x, acc[3][0]);
      acc[3][1] = fmaf(av.w, bv.y, acc[3][1]);
      acc[3][2] = fmaf(av.w, bv.z, acc[3][2]);
      acc[3][3] = fmaf(av.w, bv.w, acc[3][3]);
    }
    __syncthreads();
  }

  const float4 bias = *(const float4*)(B + j0 + tx * 4);
#pragma unroll
  for (int r = 0; r < 4; ++r) {
    const int i = i0 + ty * 4 + r;
    if (i < N_NODES) {
      const float4 o = make_float4(acc[r][0] + bias.x, acc[r][1] + bias.y,
                                   acc[r][2] + bias.z, acc[r][3] + bias.w);
      *(float4*)(H + (size_t)i * HID + j0 + tx * 4) = o;
    }
  }
}

// ---------------- per-edge scatter: agg[dst] += h[src], deg[dst] += 1 ----------------
// One wave per edge; lane l handles columns 2l, 2l+1 (coalesced 512B per edge).
__global__ __launch_bounds__(256) void scatter_k(const int* __restrict__ EI,
                                                 const float* __restrict__ H,
                                                 float* __restrict__ agg,
                                                 float* __restrict__ deg) {
  const int gw = (int)(((size_t)blockIdx.x * blockDim.x + threadIdx.x) >> 6);
  const int lane = threadIdx.x & 63;
  if (gw >= N_EDGES) return;
  const int dst = EI[gw];            // row 0 = destination
  const int src = EI[N_EDGES + gw];  // row 1 = source
  const float2 hv = *(const float2*)(H + (size_t)src * HID + lane * 2);
  float* p = agg + (size_t)dst * HID + lane * 2;
  atomicAdd(p, hv.x);
  atomicAdd(p + 1, hv.y);
  if (lane == 0) atomicAdd(deg + dst, 1.0f);
}

// ---------------- out = (h + agg) / (deg + 1), in place over h ----------------
__global__ __launch_bounds__(256) void final_k(float* __restrict__ out,
                                               const float* __restrict__ agg,
                                               const float* __restrict__ deg) {
  const size_t n4 = (size_t)N_NODES * HID / 4;
  const size_t stride = (size_t)gridDim.x * blockDim.x;
  for (size_t v = (size_t)blockIdx.x * blockDim.x + threadIdx.x; v < n4; v += stride) {
    const size_t node = v >> 5;  // 32 float4 per node row
    const float inv = 1.0f / (deg[node] + 1.0f);
    const float4 h = ((const float4*)out)[v];
    const float4 a = ((const float4*)agg)[v];
    ((float4*)out)[v] =
        make_float4((h.x + a.x) * inv, (h.y + a.y) * inv, (h.z + a.z) * inv,
                    (h.w + a.w) * inv);
  }
}

extern "C" void kernel_launch(void* const* d_in, const int* in_sizes, int n_in,
                              void* d_out, int out_size, void* d_ws, size_t ws_size,
                              hipStream_t stream) {
  const float* X = (const float*)d_in[0];  // [N_NODES, HID]
  const int* EI = (const int*)d_in[1];     // [2, N_EDGES]
  const float* W = (const float*)d_in[2];  // [HID, HID]
  const float* B = (const float*)d_in[3];  // [HID]

  float* H = (float*)d_out;                 // h lives in d_out (rewritten fully)
  float* agg = (float*)d_ws;                // [N_NODES, HID]
  float* deg = agg + (size_t)N_NODES * HID; // [N_NODES]

  zero_ws_k<<<2048, 256, 0, stream>>>((float4*)agg, deg);
  gemm_k<<<dim3((N_NODES + 63) / 64, HID / 64), 256, 0, stream>>>(X, W, B, H);
  scatter_k<<<(N_EDGES + 3) / 4, 256, 0, stream>>>(EI, H, agg, deg);
  final_k<<<2048, 256, 0, stream>>>(H, agg, deg);
}

// Round 2
// 155.362 us; speedup vs baseline: 4.7814x; 4.7814x over previous
//
#include <hip/hip_runtime.h>

#define N_NODES 50000
#define N_EDGES 800000
#define HID 128
#define CAP 64      // per-node bucket capacity (Poisson(16) -> P(deg>64) ~ 1e-18)
#define OVF_CAP 8192

// ---------------- bucket edges by dst: buckets[dst][pos] = src ----------------
__global__ __launch_bounds__(256) void bucket_k(const int* __restrict__ EI,
                                                int* __restrict__ buckets,
                                                int* __restrict__ cnt,
                                                int* __restrict__ ovf_cnt,
                                                int* __restrict__ ovf) {
  const int e = blockIdx.x * blockDim.x + threadIdx.x;
  if (e >= N_EDGES) return;
  const int dst = EI[e];            // row 0 = destination
  const int src = EI[N_EDGES + e];  // row 1 = source
  const int pos = atomicAdd(cnt + dst, 1);
  if (pos < CAP) {
    buckets[(size_t)dst * CAP + pos] = src;
  } else {
    const int oi = atomicAdd(ovf_cnt, 1);
    if (oi < OVF_CAP) ovf[oi] = e;
  }
}

// ---------------- Y[d] = (X[d] + sum_src X[src]) / (1+deg[d]) ----------------
// One wave per node; lane l owns columns 2l, 2l+1 (coalesced 512B per row read).
__global__ __launch_bounds__(256) void gather_k(const float* __restrict__ X,
                                                const int* __restrict__ buckets,
                                                const int* __restrict__ cnt,
                                                float* __restrict__ Y) {
  const int w = (int)(((size_t)blockIdx.x * blockDim.x + threadIdx.x) >> 6);
  const int lane = threadIdx.x & 63;
  if (w >= N_NODES) return;
  const int deg = cnt[w];
  const int m = deg < CAP ? deg : CAP;
  int src = 0;
  if (lane < m) src = buckets[(size_t)w * CAP + lane];
  float2 acc = *(const float2*)(X + (size_t)w * HID + lane * 2);
#pragma unroll 4
  for (int j = 0; j < m; ++j) {
    const int s = __shfl(src, j);
    const float2 v = *(const float2*)(X + (size_t)s * HID + lane * 2);
    acc.x += v.x;
    acc.y += v.y;
  }
  const float inv = 1.0f / (float)(deg + 1);
  acc.x *= inv;
  acc.y *= inv;
  *(float2*)(Y + (size_t)w * HID + lane * 2) = acc;
}

// ---------------- out = Y @ W^T + b, IN PLACE over Y (d_out) ----------------
// 64 rows x ALL 128 cols per block -> each block reads only its own 64 rows of
// Y and rewrites exactly those rows: in-place safe (no cross-block row reuse).
// 256 threads: tx = col-group (16 x 8 cols), ty = row-group (16 x 4 rows).
__global__ __launch_bounds__(256) void gemm_k(const float* __restrict__ Y,
                                              const float* __restrict__ W,
                                              const float* __restrict__ B,
                                              float* __restrict__ OUT) {
  __shared__ __align__(16) float As[32][68];
  __shared__ __align__(16) float Bs[32][132];
  const int t = threadIdx.x;
  const int tx = t & 15;  // 0..15 -> cols [tx*8, tx*8+8)
  const int ty = t >> 4;  // 0..15 -> rows [ty*4, ty*4+4)
  const int i0 = blockIdx.x * 64;
  float acc[4][8];
#pragma unroll
  for (int r = 0; r < 4; ++r)
#pragma unroll
    for (int c = 0; c < 8; ++c) acc[r][c] = 0.f;

  for (int kc = 0; kc < HID; kc += 32) {
    // stage A: 64 rows x 32 k = 512 float4, 2 per thread
#pragma unroll
    for (int it = 0; it < 2; ++it) {
      const int v = t + it * 256;
      const int row = v >> 3;
      const int c4 = v & 7;
      float4 a = make_float4(0.f, 0.f, 0.f, 0.f);
      if (i0 + row < N_NODES)
        a = *(const float4*)(Y + (size_t)(i0 + row) * HID + kc + c4 * 4);
      As[c4 * 4 + 0][row] = a.x;
      As[c4 * 4 + 1][row] = a.y;
      As[c4 * 4 + 2][row] = a.z;
      As[c4 * 4 + 3][row] = a.w;
    }
    // stage B: 128 rows(j) x 32 k = 1024 float4, 4 per thread
#pragma unroll
    for (int it = 0; it < 4; ++it) {
      const int v = t + it * 256;
      const int j = v >> 3;
      const int c4 = v & 7;
      const float4 w = *(const float4*)(W + (size_t)j * HID + kc + c4 * 4);
      Bs[c4 * 4 + 0][j] = w.x;
      Bs[c4 * 4 + 1][j] = w.y;
      Bs[c4 * 4 + 2][j] = w.z;
      Bs[c4 * 4 + 3][j] = w.w;
    }
    __syncthreads();
#pragma unroll
    for (int k = 0; k < 32; ++k) {
      const float4 av = *(const float4*)&As[k][ty * 4];
      const float4 b0 = *(const float4*)&Bs[k][tx * 8];
      const float4 b1 = *(const float4*)&Bs[k][tx * 8 + 4];
      const float a0 = av.x, a1 = av.y, a2 = av.z, a3 = av.w;
      acc[0][0] = fmaf(a0, b0.x, acc[0][0]);
      acc[0][1] = fmaf(a0, b0.y, acc[0][1]);
      acc[0][2] = fmaf(a0, b0.z, acc[0][2]);
      acc[0][3] = fmaf(a0, b0.w, acc[0][3]);
      acc[0][4] = fmaf(a0, b1.x, acc[0][4]);
      acc[0][5] = fmaf(a0, b1.y, acc[0][5]);
      acc[0][6] = fmaf(a0, b1.z, acc[0][6]);
      acc[0][7] = fmaf(a0, b1.w, acc[0][7]);
      acc[1][0] = fmaf(a1, b0.x, acc[1][0]);
      acc[1][1] = fmaf(a1, b0.y, acc[1][1]);
      acc[1][2] = fmaf(a1, b0.z, acc[1][2]);
      acc[1][3] = fmaf(a1, b0.w, acc[1][3]);
      acc[1][4] = fmaf(a1, b1.x, acc[1][4]);
      acc[1][5] = fmaf(a1, b1.y, acc[1][5]);
      acc[1][6] = fmaf(a1, b1.z, acc[1][6]);
      acc[1][7] = fmaf(a1, b1.w, acc[1][7]);
      acc[2][0] = fmaf(a2, b0.x, acc[2][0]);
      acc[2][1] = fmaf(a2, b0.y, acc[2][1]);
      acc[2][2] = fmaf(a2, b0.z, acc[2][2]);
      acc[2][3] = fmaf(a2, b0.w, acc[2][3]);
      acc[2][4] = fmaf(a2, b1.x, acc[2][4]);
      acc[2][5] = fmaf(a2, b1.y, acc[2][5]);
      acc[2][6] = fmaf(a2, b1.z, acc[2][6]);
      acc[2][7] = fmaf(a2, b1.w, acc[2][7]);
      acc[3][0] = fmaf(a3, b0.x, acc[3][0]);
      acc[3][1] = fmaf(a3, b0.y, acc[3][1]);
      acc[3][2] = fmaf(a3, b0.z, acc[3][2]);
      acc[3][3] = fmaf(a3, b0.w, acc[3][3]);
      acc[3][4] = fmaf(a3, b1.x, acc[3][4]);
      acc[3][5] = fmaf(a3, b1.y, acc[3][5]);
      acc[3][6] = fmaf(a3, b1.z, acc[3][6]);
      acc[3][7] = fmaf(a3, b1.w, acc[3][7]);
    }
    __syncthreads();
  }

  const float4 bias0 = *(const float4*)(B + tx * 8);
  const float4 bias1 = *(const float4*)(B + tx * 8 + 4);
#pragma unroll
  for (int r = 0; r < 4; ++r) {
    const int i = i0 + ty * 4 + r;
    if (i < N_NODES) {
      float4 o0 = make_float4(acc[r][0] + bias0.x, acc[r][1] + bias0.y,
                              acc[r][2] + bias0.z, acc[r][3] + bias0.w);
      float4 o1 = make_float4(acc[r][4] + bias1.x, acc[r][5] + bias1.y,
                              acc[r][6] + bias1.z, acc[r][7] + bias1.w);
      *(float4*)(OUT + (size_t)i * HID + tx * 8) = o0;
      *(float4*)(OUT + (size_t)i * HID + tx * 8 + 4) = o1;
    }
  }
}

// ---------------- overflow fixup (never taken in practice; exact) ----------------
// out[dst] += (X[src]/(1+deg[dst])) @ W^T  for each overflowed edge.
__global__ __launch_bounds__(64) void fixup_k(const int* __restrict__ EI,
                                              const float* __restrict__ X,
                                              const float* __restrict__ W,
                                              const int* __restrict__ cnt,
                                              const int* __restrict__ ovf_cnt,
                                              const int* __restrict__ ovf,
                                              float* __restrict__ OUT) {
  const int n = *ovf_cnt;
  const int lane = threadIdx.x & 63;
  for (int i = blockIdx.x; i < n; i += gridDim.x) {
    const int e = ovf[i];
    const int dst = EI[e];
    const int src = EI[N_EDGES + e];
    const float inv = 1.0f / (float)(cnt[dst] + 1);
    float s0 = 0.f, s1 = 0.f;
    const int c0 = lane * 2, c1 = lane * 2 + 1;
    for (int k = 0; k < HID; ++k) {
      const float xv = X[(size_t)src * HID + k];
      s0 = fmaf(xv, W[(size_t)c0 * HID + k], s0);
      s1 = fmaf(xv, W[(size_t)c1 * HID + k], s1);
    }
    atomicAdd(OUT + (size_t)dst * HID + c0, s0 * inv);
    atomicAdd(OUT + (size_t)dst * HID + c1, s1 * inv);
  }
}

extern "C" void kernel_launch(void* const* d_in, const int* in_sizes, int n_in,
                              void* d_out, int out_size, void* d_ws, size_t ws_size,
                              hipStream_t stream) {
  const float* X = (const float*)d_in[0];  // [N_NODES, HID]
  const int* EI = (const int*)d_in[1];     // [2, N_EDGES]
  const float* W = (const float*)d_in[2];  // [HID, HID]
  const float* B = (const float*)d_in[3];  // [HID]

  float* OUT = (float*)d_out;  // holds Y after gather, final out after gemm

  // ws layout: buckets[N*CAP] | cnt[N] | ovf_cnt[1] | ovf[OVF_CAP]
  int* buckets = (int*)d_ws;
  int* cnt = buckets + (size_t)N_NODES * CAP;
  int* ovf_cnt = cnt + N_NODES;
  int* ovf = ovf_cnt + 1;

  // zero cnt + ovf_cnt (ovf payload needs no init)
  hipMemsetAsync(cnt, 0, (size_t)(N_NODES + 1) * sizeof(int), stream);

  bucket_k<<<(N_EDGES + 255) / 256, 256, 0, stream>>>(EI, buckets, cnt, ovf_cnt, ovf);
  gather_k<<<(N_NODES * 64 + 255) / 256, 256, 0, stream>>>(X, buckets, cnt, OUT);
  gemm_k<<<(N_NODES + 63) / 64, 256, 0, stream>>>(OUT, W, B, OUT);
  fixup_k<<<64, 64, 0, stream>>>(EI, X, W, cnt, ovf_cnt, ovf, OUT);
}